// Round 3
// baseline (969.057 us; speedup 1.0000x reference)
//
#include <hip/hip_runtime.h>
#include <hip/hip_bf16.h>

#define BB 32
#define SS 2048
#define DD 1024
#define UU 1024

typedef __attribute__((ext_vector_type(8))) short bf16x8;
typedef __attribute__((ext_vector_type(4))) float f32x4;

static __device__ __forceinline__ unsigned short f32_to_bf16(float f) {
    unsigned int x = __builtin_bit_cast(unsigned int, f);
    unsigned int r = x + 0x7FFFu + ((x >> 16) & 1u);
    return (unsigned short)(r >> 16);
}

// K0: W1 [D][U] f32 -> W1t [U][D] bf16
__global__ void k0_w1t(const float* __restrict__ W1, unsigned short* __restrict__ W1t) {
    __shared__ unsigned short tile[64][65];
    int u0 = blockIdx.x * 64;
    int d0 = blockIdx.y * 64;
    int t = threadIdx.x;
    int j = t & 63;
    int i0 = (t >> 6) * 16;
    for (int ii = 0; ii < 16; ++ii) {
        int d = d0 + i0 + ii;
        tile[i0 + ii][j] = f32_to_bf16(W1[d * UU + u0 + j]);
    }
    __syncthreads();
    int i2 = t & 63;
    int j0 = (t >> 6) * 16;
    for (int jj = 0; jj < 16; ++jj)
        W1t[(size_t)(u0 + j0 + jj) * DD + d0 + i2] = tile[i2][j0 + jj];
}

// K1: pqb[b][u] = b1[u] + b2[u] + sum_d q[b][d]*W2[d][u]
__global__ void k1_projq(const float* __restrict__ query, const float* __restrict__ W2,
                         const float* __restrict__ b1, const float* __restrict__ b2,
                         float* __restrict__ pqb) {
    int u = blockIdx.x * 256 + threadIdx.x;
    int b = blockIdx.y;
    float acc = b1[u] + b2[u];
    const float* q = query + b * DD;
    for (int d = 0; d < DD; ++d)
        acc = fmaf(q[d], W2[d * UU + u], acc);
    pqb[b * UU + u] = acc;
}

// K2: fused score GEMM: scorep[slot][row] partial of sum_u tanh(values@W1 + pqb) * V
#define BM 128
#define BN 256
#define BK 64

__launch_bounds__(256, 2)
__global__ void k2_score(const float* __restrict__ values,
                         const unsigned short* __restrict__ W1t,
                         const float* __restrict__ pqb,
                         const float* __restrict__ V,
                         float* __restrict__ scorep) {
    __shared__ __align__(16) unsigned char lds[49152]; // A: [0,16K) [128][64]bf16 swz; B: [16K,48K) [256][64]bf16 swz
    const int t = threadIdx.x;
    const int rb = blockIdx.x;
    const int ub = blockIdx.y;
    const int r0 = rb * BM;          // global row (b*2048+s)
    const int b = r0 >> 11;
    const int u0 = ub * BN;

    f32x4 acc[4][8];
    #pragma unroll
    for (int i = 0; i < 4; ++i)
        #pragma unroll
        for (int j = 0; j < 8; ++j) { f32x4 z = {0.f,0.f,0.f,0.f}; acc[i][j] = z; }

    const int w = t >> 6;
    const int l = t & 63;
    const int rw = (w >> 1) * 64;   // wave row offset in tile
    const int uw = (w & 1) * 128;   // wave col offset in tile

    const int sa_row = t >> 4;          // A staging: 16 rows/pass
    const int sa_col = (t & 15) * 4;    // 4 f32 per thread
    const int sb_row = t >> 3;          // B staging: 32 rows/pass
    const int sb_col = (t & 7) * 8;     // 8 bf16 per thread

    for (int kt = 0; kt < DD / BK; ++kt) {
        int k0 = kt * BK;
        __syncthreads();
        // stage A (values f32 -> bf16, swizzled)
        #pragma unroll
        for (int it = 0; it < 8; ++it) {
            int row = sa_row + it * 16;
            float4 v = *(const float4*)(values + (size_t)(r0 + row) * DD + k0 + sa_col);
            unsigned long long pk =
                (unsigned long long)f32_to_bf16(v.x) |
                ((unsigned long long)f32_to_bf16(v.y) << 16) |
                ((unsigned long long)f32_to_bf16(v.z) << 32) |
                ((unsigned long long)f32_to_bf16(v.w) << 48);
            int jb = sa_col * 2;
            int addr = row * 128 + (jb ^ ((row & 7) << 4));
            *(unsigned long long*)(lds + addr) = pk;
        }
        // stage B (W1t bf16, swizzled)
        #pragma unroll
        for (int it = 0; it < 8; ++it) {
            int urow = sb_row + it * 32;
            uint4 vv = *(const uint4*)(W1t + (size_t)(u0 + urow) * DD + k0 + sb_col);
            int jb = sb_col * 2;
            int addr = 16384 + urow * 128 + (jb ^ ((urow & 7) << 4));
            *(uint4*)(lds + addr) = vv;
        }
        __syncthreads();
        #pragma unroll
        for (int kk = 0; kk < 2; ++kk) {
            int kbyte = kk * 64 + (l >> 4) * 16;
            bf16x8 af[4];
            #pragma unroll
            for (int mf = 0; mf < 4; ++mf) {
                int row = rw + mf * 16 + (l & 15);
                int addr = row * 128 + (kbyte ^ ((row & 7) << 4));
                af[mf] = *(const bf16x8*)(lds + addr);
            }
            #pragma unroll
            for (int nf = 0; nf < 8; ++nf) {
                int urow = uw + nf * 16 + (l & 15);
                int addr = 16384 + urow * 128 + (kbyte ^ ((urow & 7) << 4));
                bf16x8 bfv = *(const bf16x8*)(lds + addr);
                #pragma unroll
                for (int mf = 0; mf < 4; ++mf)
                    acc[mf][nf] = __builtin_amdgcn_mfma_f32_16x16x32_bf16(af[mf], bfv, acc[mf][nf], 0, 0, 0);
            }
        }
    }

    // epilogue: tanh + dot with V, per-row partial
    float pq_l[8], V_l[8];
    #pragma unroll
    for (int nf = 0; nf < 8; ++nf) {
        int u = u0 + uw + nf * 16 + (l & 15);
        pq_l[nf] = pqb[b * UU + u];
        V_l[nf] = V[u];
    }
    float rowacc[16];
    #pragma unroll
    for (int i = 0; i < 16; ++i) rowacc[i] = 0.f;
    #pragma unroll
    for (int mf = 0; mf < 4; ++mf)
        #pragma unroll
        for (int nf = 0; nf < 8; ++nf)
            #pragma unroll
            for (int r = 0; r < 4; ++r)
                rowacc[mf * 4 + r] += tanhf(acc[mf][nf][r] + pq_l[nf]) * V_l[nf];
    #pragma unroll
    for (int m = 8; m >= 1; m >>= 1)
        #pragma unroll
        for (int i = 0; i < 16; ++i)
            rowacc[i] += __shfl_xor(rowacc[i], m, 64);
    if ((l & 15) == 0) {
        int g = l >> 4;
        int slot = ub * 2 + (w & 1);
        #pragma unroll
        for (int mf = 0; mf < 4; ++mf)
            #pragma unroll
            for (int r = 0; r < 4; ++r) {
                int row = r0 + rw + mf * 16 + g * 4 + r;
                scorep[(size_t)slot * (BB * SS) + row] = rowacc[mf * 4 + r];
            }
    }
}

// K3: softmax over S per batch; writes attention weights
__global__ void k3_softmax(const float* __restrict__ scorep, float* __restrict__ attn) {
    int b = blockIdx.x;
    int t = threadIdx.x;
    __shared__ float red[4];
    __shared__ float red2[4];
    float sl[8];
    float mx = -1e30f;
    #pragma unroll
    for (int i = 0; i < 8; ++i) {
        int s = t + i * 256;
        float a = 0.f;
        #pragma unroll
        for (int slot = 0; slot < 8; ++slot)
            a += scorep[slot * (BB * SS) + b * SS + s];
        sl[i] = a;
        mx = fmaxf(mx, a);
    }
    for (int m = 32; m >= 1; m >>= 1) mx = fmaxf(mx, __shfl_xor(mx, m, 64));
    if ((t & 63) == 0) red[t >> 6] = mx;
    __syncthreads();
    mx = fmaxf(fmaxf(red[0], red[1]), fmaxf(red[2], red[3]));
    float sum = 0.f;
    #pragma unroll
    for (int i = 0; i < 8; ++i) { sl[i] = __expf(sl[i] - mx); sum += sl[i]; }
    for (int m = 32; m >= 1; m >>= 1) sum += __shfl_xor(sum, m, 64);
    if ((t & 63) == 0) red2[t >> 6] = sum;
    __syncthreads();
    sum = red2[0] + red2[1] + red2[2] + red2[3];
    float inv = 1.f / sum;
    #pragma unroll
    for (int i = 0; i < 8; ++i)
        attn[b * SS + t + i * 256] = sl[i] * inv;
}

// K4a: partial context over s-chunks of 128
__global__ void k4a_ctx(const float* __restrict__ values, const float* __restrict__ attn,
                        float* __restrict__ ctxp) {
    int sc = blockIdx.x;  // 0..15
    int b = blockIdx.y;
    int t = threadIdx.x;
    __shared__ float wsm[128];
    if (t < 128) wsm[t] = attn[b * SS + sc * 128 + t];
    __syncthreads();
    float ax = 0.f, ay = 0.f, az = 0.f, aw = 0.f;
    const float4* vp = (const float4*)(values + (size_t)b * SS * DD + (size_t)sc * 128 * DD) + t;
    for (int s = 0; s < 128; ++s) {
        float4 v = vp[s * (DD / 4)];
        float wv = wsm[s];
        ax = fmaf(wv, v.x, ax); ay = fmaf(wv, v.y, ay);
        az = fmaf(wv, v.z, az); aw = fmaf(wv, v.w, aw);
    }
    float4 o; o.x = ax; o.y = ay; o.z = az; o.w = aw;
    *(float4*)(ctxp + (size_t)(sc * BB + b) * DD + t * 4) = o;
}

// K4b: reduce 16 partials
__global__ void k4b_reduce(const float* __restrict__ ctxp, float* __restrict__ ctx) {
    int i = blockIdx.x * 256 + threadIdx.x; // b*1024+d
    float a = 0.f;
    #pragma unroll
    for (int sc = 0; sc < 16; ++sc)
        a += ctxp[sc * (BB * DD) + i];
    ctx[i] = a;
}

extern "C" void kernel_launch(void* const* d_in, const int* in_sizes, int n_in,
                              void* d_out, int out_size, void* d_ws, size_t ws_size,
                              hipStream_t stream) {
    const float* query  = (const float*)d_in[0];
    const float* values = (const float*)d_in[1];
    const float* W1     = (const float*)d_in[2];
    const float* b1     = (const float*)d_in[3];
    const float* W2     = (const float*)d_in[4];
    const float* b2     = (const float*)d_in[5];
    const float* V      = (const float*)d_in[6];
    // d_in[7] = bV: softmax-invariant, attention output unaffected; context unaffected.

    float* out_ctx  = (float*)d_out;              // [32][1024]
    float* out_attn = (float*)d_out + BB * DD;    // [32][2048]

    char* wsb = (char*)d_ws;
    unsigned short* W1t = (unsigned short*)wsb;                         // 2 MB
    float* pqb    = (float*)(wsb + (2u << 20));                         // 128 KB
    float* scorep = (float*)(wsb + (2u << 20) + (128u << 10));          // 2 MB (8 slots x 65536)
    float* ctxp   = (float*)(wsb + (4u << 20) + (128u << 10));          // 2 MB (16 x 32 x 1024)

    hipLaunchKernelGGL(k0_w1t,     dim3(16, 16), dim3(256), 0, stream, W1, W1t);
    hipLaunchKernelGGL(k1_projq,   dim3(4, 32),  dim3(256), 0, stream, query, W2, b1, b2, pqb);
    hipLaunchKernelGGL(k2_score,   dim3(512, 4), dim3(256), 0, stream, values, W1t, pqb, V, scorep);
    hipLaunchKernelGGL(k3_softmax, dim3(32),     dim3(256), 0, stream, scorep, out_attn);
    hipLaunchKernelGGL(k4a_ctx,    dim3(16, 32), dim3(256), 0, stream, values, out_attn, ctxp);
    hipLaunchKernelGGL(k4b_reduce, dim3(128),    dim3(256), 0, stream, ctxp, out_ctx);
}